// Round 5
// baseline (112.437 us; speedup 1.0000x reference)
//
#include <hip/hip_runtime.h>
#include <math.h>

#define BATCH 4
#define NPTS 8192
#define TPB 512
#define RPB 256                      // rows per block
#define NBLK (NPTS / RPB)            // 32 row-blocks per (b,dir)
#define CHUNK_COLS 512               // one column per thread per chunk
#define NCHUNK (NPTS / CHUNK_COLS)   // 16

// ---------------------------------------------------------------------------
// PAIRING-PROOF MFMA Chamfer.
//
// R4 proved (finite probe-keyed result) that the A row-map is lane&31-pure
// and the epilogue is layout-correct, yet D is still ~20% off.  The one
// remaining unverified contract is the A<->B k-slot bijection.  This kernel
// needs NO intra-half pairing assumption: every product has one operand
// UNIFORM across its 8-slot lane-half, so any within-half slot scramble
// leaves the half's partial sum unchanged:
//   MFMA_d (d=0,1,2): A half0 = xh_d (x8), half1 = xm_d (x8);
//                     B (both halves) = [-2yh_d, -2ym_d, 0 x6]
//                     -> xh_d*(-2y_d) + xm_d*(-2y_d) = -2 x_d y_d
//   MFMA_4:           A half0 = [x2h, x2m, 0 x6], half1 = ones;
//                     B group0 = ones,  group1 = [qh, qm, 0 x6]
//                     -> x^2 (B-uniform-safe) + y^2 (A-uniform-safe)
// Accumulated in one f32x16 acc -> D = d2 exactly (bf16-split error ~1e-4).
// Half-correspondence (A half h pairs B half h or crossed) is PROBED at
// runtime and handled either way; violations inject sentinel magnitudes
// into the output (1e6 = mixed halves, 1e9 = row-map impurity) as a blind
// debug channel.  Also removed this round: v_min3 inline asm (-> fminf),
// b128 fragment staging (-> SoA ds_read_b32, conflict-free broadcast),
// LDS double-buffer (-> single buffer, 2 barriers/chunk).
// ---------------------------------------------------------------------------

typedef __attribute__((ext_vector_type(8))) short bf16x8;   // 8 bf16 = 4 VGPR
typedef __attribute__((ext_vector_type(16))) float f32x16;  // 32x32 acc

static_assert(sizeof(bf16x8) == 16, "frag size");

__device__ inline unsigned short bf16_rne(float v) {
  unsigned u = __builtin_bit_cast(unsigned, v);
  return (unsigned short)((u + 0x7FFFu + ((u >> 16) & 1u)) >> 16);
}
__device__ inline float bf16_up(unsigned short u) {
  return __builtin_bit_cast(float, (unsigned)u << 16);
}

#define ONE_BF16 ((short)0x3F80)      // 1.0
#define HALF_BF16 ((short)0x3F00)     // 0.5
#define QUARTER_BF16 ((short)0x3E80)  // 0.25
#define SIXT_BF16 ((short)0x3D80)     // 0.0625

__device__ inline bf16x8 rep8(short s) {
  bf16x8 v;
  v[0] = s; v[1] = s; v[2] = s; v[3] = s;
  v[4] = s; v[5] = s; v[6] = s; v[7] = s;
  return v;
}
__device__ inline bf16x8 pair0(short a, short b) {
  bf16x8 v = {};
  v[0] = a; v[1] = b;
  return v;
}
__device__ inline unsigned pack2(unsigned short lo, unsigned short hi) {
  return (unsigned)lo | ((unsigned)hi << 16);
}

__global__ __launch_bounds__(TPB, 2) void chamfer_main(
    const float* __restrict__ pred, const float* __restrict__ label,
    float* __restrict__ blocksum) {
  // SoA staging: [d0|d1|d2|q][col] packed (h,m) bf16 pairs. Reads are
  // 32 consecutive dwords per lane-half -> banks 0..31, halves broadcast.
  __shared__ unsigned lds_w[4][CHUNK_COLS];
  __shared__ unsigned smin_u[RPB];  // per-row min of d2, uint-ordered
  __shared__ float ssum[8];

  const int tid = threadIdx.x;
  const int lane = tid & 63;
  const int w = tid >> 6;   // wave 0..7
  const int rg = w & 3;     // row group of 64 rows
  const int ch = w >> 2;    // which 8-tile half of each chunk
  const int kg = lane >> 5; // physical lane-half
  const int b = blockIdx.y;
  const int dir = blockIdx.z;
  const int rowBase = blockIdx.x * RPB;

  const float* __restrict__ rows = dir ? label : pred;
  const float* __restrict__ cols = dir ? pred : label;

  if (tid < RPB) smin_u[tid] = 0x7F800000u;  // +inf

  // ---- A-side fragments, per row-tile rt in {0,1} ----
  bf16x8 aD[2][3];  // MFMA_d operand: half0 = xh_d, half1 = xm_d (replicated)
  bf16x8 a4[2];     // MFMA_4 operand: half0 = [x2h,x2m,0..], half1 = ones
#pragma unroll
  for (int rt = 0; rt < 2; ++rt) {
    const int rrow = rowBase + rg * 64 + rt * 32 + (lane & 31);
    const float* p = rows + ((size_t)b * NPTS + rrow) * 3;
    const float x0 = p[0], x1 = p[1], x2 = p[2];
    const unsigned short xh0 = bf16_rne(x0);
    const unsigned short xm0 = bf16_rne(x0 - bf16_up(xh0));
    const unsigned short xh1 = bf16_rne(x1);
    const unsigned short xm1 = bf16_rne(x1 - bf16_up(xh1));
    const unsigned short xh2 = bf16_rne(x2);
    const unsigned short xm2 = bf16_rne(x2 - bf16_up(xh2));
    const float xx = x0 * x0 + x1 * x1 + x2 * x2;
    const unsigned short x2h = bf16_rne(xx);
    const unsigned short x2m = bf16_rne(xx - bf16_up(x2h));
    aD[rt][0] = rep8((short)(kg ? xm0 : xh0));
    aD[rt][1] = rep8((short)(kg ? xm1 : xh1));
    aD[rt][2] = rep8((short)(kg ? xm2 : xh2));
    a4[rt] = kg ? rep8(ONE_BF16) : pair0((short)x2h, (short)x2m);
  }

  const f32x16 zero = {};
  float diag = 0.0f;

  // ---- probe 1: row labels (A fully uniform per lane -> valid under any
  //      k-map / pairing / half-crossing).  Non-integer => impurity sentinel.
  int rowid[16];
  {
    const bf16x8 pa = rep8((short)bf16_rne((float)(lane & 31)));
    const bf16x8 pb = rep8(SIXT_BF16);
    const f32x16 pr = __builtin_amdgcn_mfma_f32_32x32x16_bf16(pa, pb, zero, 0, 0, 0);
#pragma unroll
    for (int i = 0; i < 16; ++i) {
      const float r = pr[i];
      const int ri = (int)(r + 0.5f);
      rowid[i] = ri & 31;
      if (fabsf(r - (float)ri) > 0.01f) diag += 1.0e9f;
    }
  }
  // ---- probe 2: half correspondence.  A: half0=1, half1=0.
  //      B: half0=0.25, half1=0.5.  D = 2 aligned, 4 crossed, else mixed.
  int crossed;
  {
    const bf16x8 pa = rep8(kg ? (short)0 : ONE_BF16);
    const bf16x8 pb = rep8(kg ? HALF_BF16 : QUARTER_BF16);
    const f32x16 ph = __builtin_amdgcn_mfma_f32_32x32x16_bf16(pa, pb, zero, 0, 0, 0);
    const float hp = ph[0];
    crossed = (hp > 3.0f) ? 1 : 0;
    if (fabsf(hp - 2.0f) > 0.05f && fabsf(hp - 4.0f) > 0.05f) diag += 1.0e6f;
  }
  // B-side logical group of this lane for MFMA_4 (only operand that differs
  // by group): group0 must carry ones, group1 the y^2 pair.
  const int bg = kg ^ crossed;

  float mn[2][16];
#pragma unroll
  for (int rt = 0; rt < 2; ++rt)
#pragma unroll
    for (int i = 0; i < 16; ++i) mn[rt][i] = 3.0e38f;

  for (int c = 0; c < NCHUNK; ++c) {
    __syncthreads();  // previous chunk fully consumed
    {
      // Stage: one column per thread, SoA packed (h,m) pairs.
      const float* q = cols + ((size_t)b * NPTS + c * CHUNK_COLS + tid) * 3;
      const float y0 = q[0], y1 = q[1], y2 = q[2];
      const float a0 = -2.0f * y0, a1 = -2.0f * y1, a2 = -2.0f * y2;
      const unsigned short h0 = bf16_rne(a0);
      const unsigned short m0 = bf16_rne(a0 - bf16_up(h0));
      const unsigned short h1 = bf16_rne(a1);
      const unsigned short m1 = bf16_rne(a1 - bf16_up(h1));
      const unsigned short h2 = bf16_rne(a2);
      const unsigned short m2 = bf16_rne(a2 - bf16_up(h2));
      const float qq = y0 * y0 + y1 * y1 + y2 * y2;
      const unsigned short qh = bf16_rne(qq);
      const unsigned short qm = bf16_rne(qq - bf16_up(qh));
      lds_w[0][tid] = pack2(h0, m0);
      lds_w[1][tid] = pack2(h1, m1);
      lds_w[2][tid] = pack2(h2, m2);
      lds_w[3][tid] = pack2(qh, qm);
    }
    __syncthreads();  // chunk staged

    // Wave's col-tiles: ch*8 .. ch*8+7, processed in pairs.
#pragma unroll
    for (int p = 0; p < 8; p += 2) {
      const int c0 = (ch * 8 + p) * 32 + (lane & 31);
      const int c1 = c0 + 32;
      const unsigned u00 = lds_w[0][c0], u01 = lds_w[1][c0];
      const unsigned u02 = lds_w[2][c0], u0q = lds_w[3][c0];
      const unsigned u10 = lds_w[0][c1], u11 = lds_w[1][c1];
      const unsigned u12 = lds_w[2][c1], u1q = lds_w[3][c1];
      const bf16x8 b00 = pair0((short)(u00 & 0xFFFF), (short)(u00 >> 16));
      const bf16x8 b01 = pair0((short)(u01 & 0xFFFF), (short)(u01 >> 16));
      const bf16x8 b02 = pair0((short)(u02 & 0xFFFF), (short)(u02 >> 16));
      const bf16x8 b0q = bg ? pair0((short)(u0q & 0xFFFF), (short)(u0q >> 16))
                            : rep8(ONE_BF16);
      const bf16x8 b10 = pair0((short)(u10 & 0xFFFF), (short)(u10 >> 16));
      const bf16x8 b11 = pair0((short)(u11 & 0xFFFF), (short)(u11 >> 16));
      const bf16x8 b12 = pair0((short)(u12 & 0xFFFF), (short)(u12 >> 16));
      const bf16x8 b1q = bg ? pair0((short)(u1q & 0xFFFF), (short)(u1q >> 16))
                            : rep8(ONE_BF16);
#pragma unroll
      for (int rt = 0; rt < 2; ++rt) {
        f32x16 A0 = __builtin_amdgcn_mfma_f32_32x32x16_bf16(aD[rt][0], b00, zero, 0, 0, 0);
        A0 = __builtin_amdgcn_mfma_f32_32x32x16_bf16(aD[rt][1], b01, A0, 0, 0, 0);
        A0 = __builtin_amdgcn_mfma_f32_32x32x16_bf16(aD[rt][2], b02, A0, 0, 0, 0);
        A0 = __builtin_amdgcn_mfma_f32_32x32x16_bf16(a4[rt],    b0q, A0, 0, 0, 0);
        f32x16 A1 = __builtin_amdgcn_mfma_f32_32x32x16_bf16(aD[rt][0], b10, zero, 0, 0, 0);
        A1 = __builtin_amdgcn_mfma_f32_32x32x16_bf16(aD[rt][1], b11, A1, 0, 0, 0);
        A1 = __builtin_amdgcn_mfma_f32_32x32x16_bf16(aD[rt][2], b12, A1, 0, 0, 0);
        A1 = __builtin_amdgcn_mfma_f32_32x32x16_bf16(a4[rt],    b1q, A1, 0, 0, 0);
#pragma unroll
        for (int i = 0; i < 16; ++i)
          mn[rt][i] = fminf(fminf(mn[rt][i], A0[i]), A1[i]);
      }
    }
  }

  // ---- epilogue: probe-keyed per-row atomicMin (R4 structure, validated) --
#pragma unroll
  for (int rt = 0; rt < 2; ++rt)
#pragma unroll
    for (int i = 0; i < 16; ++i)
      atomicMin(&smin_u[rg * 64 + rt * 32 + rowid[i]],
                __float_as_uint(mn[rt][i]));
  __syncthreads();

  float v = diag;  // 0 in the healthy case; sentinel magnitudes otherwise
  if (tid < RPB) v += sqrtf(fmaxf(__uint_as_float(smin_u[tid]), 0.0f));
#pragma unroll
  for (int off = 32; off > 0; off >>= 1) v += __shfl_down(v, off, 64);
  if (lane == 0) ssum[w] = v;
  __syncthreads();
  if (tid == 0) {
    blocksum[((size_t)dir * BATCH + b) * NBLK + blockIdx.x] =
        ssum[0] + ssum[1] + ssum[2] + ssum[3] +
        ssum[4] + ssum[5] + ssum[6] + ssum[7];
  }
}

// One block sums the 256 per-block partials and OVERWRITES out[0]
// (deterministic, idempotent across graph replays).
__global__ __launch_bounds__(256) void chamfer_finish(
    const float* __restrict__ blocksum, float* __restrict__ out) {
  float v = blocksum[threadIdx.x];
#pragma unroll
  for (int off = 32; off > 0; off >>= 1) v += __shfl_down(v, off, 64);
  __shared__ float s4[4];
  const int wid = threadIdx.x >> 6;
  const int lane = threadIdx.x & 63;
  if (lane == 0) s4[wid] = v;
  __syncthreads();
  if (threadIdx.x == 0)
    out[0] = (s4[0] + s4[1] + s4[2] + s4[3]) * (1.0f / (float)(BATCH * NPTS));
}

extern "C" void kernel_launch(void* const* d_in, const int* in_sizes, int n_in,
                              void* d_out, int out_size, void* d_ws,
                              size_t ws_size, hipStream_t stream) {
  const float* pred = (const float*)d_in[0];
  const float* label = (const float*)d_in[1];
  float* out = (float*)d_out;
  float* blocksum = (float*)d_ws;  // 256 floats (ws >= 4 MB confirmed)

  chamfer_main<<<dim3(NBLK, BATCH, 2), TPB, 0, stream>>>(pred, label, blocksum);
  chamfer_finish<<<1, 256, 0, stream>>>(blocksum, out);
}